// Round 1
// baseline (9788.721 us; speedup 1.0000x reference)
//
#include <hip/hip_runtime.h>
#include <hip/hip_bf16.h>

#define DEV static __device__ __forceinline__

typedef unsigned short u16;
typedef __attribute__((ext_vector_type(8))) short short8;   // 8 bf16 (4 VGPRs) MFMA frag
typedef __attribute__((ext_vector_type(4))) float f32x4;    // MFMA accumulator

constexpr int V = 32000, H = 1024, B = 32, T = 256;
constexpr int BT = B * T;       // 8192 rows
constexpr int G  = 4 * H;       // 4096 gates
constexpr int NCH = V / 128;    // 250 col-chunks for softmax partials

// ---------------- workspace layout (bytes) ----------------
constexpr size_t SZ_WT    = (size_t)G * 2048 * 2;            // [4096][2048] bf16
constexpr size_t OFF_W0T  = 0;
constexpr size_t OFF_W1T  = OFF_W0T + SZ_WT;
constexpr size_t OFF_EBF  = OFF_W1T + SZ_WT;                 // [32000][1024] bf16
constexpr size_t OFF_XBF  = OFF_EBF + (size_t)V * H * 2;     // [8192][1024] bf16 (row = t*32+b)
constexpr size_t OFF_XP0  = OFF_XBF + (size_t)BT * H * 2;    // [8192][4096] f32 (row = t*32+b)
constexpr size_t OFF_H1   = OFF_XP0 + (size_t)BT * G * 4;    // [8192][1024] bf16 (row = b*256+t)
constexpr size_t OFF_HBUF = OFF_H1 + (size_t)BT * H * 2;     // [2][32][2048] bf16 (h0|h1 concat)
constexpr size_t OFF_C0   = OFF_HBUF + (size_t)2 * 32 * 2048 * 2;
constexpr size_t OFF_C1   = OFF_C0 + (size_t)32 * 1024 * 4;
constexpr size_t OFF_PMAX = OFF_C1 + (size_t)32 * 1024 * 4;  // [8192][250] f32
constexpr size_t OFF_PSUM = OFF_PMAX + (size_t)BT * NCH * 4;
constexpr size_t OFF_LOSS = OFF_PSUM + (size_t)BT * NCH * 4; // [8192] f32

DEV u16 f2bf(float x) {  // RNE f32 -> bf16 bits
  union { float f; unsigned int u; } v; v.f = x;
  unsigned int r = v.u + 0x7fffu + ((v.u >> 16) & 1u);
  return (u16)(r >> 16);
}
DEV float sigm(float x) { return 1.f / (1.f + expf(-x)); }

DEV void gload_lds16(const u16* g, u16* l) {
  // 16B per lane, LDS dest = wave-uniform base + lane*16 (linear)
  __builtin_amdgcn_global_load_lds(
      (__attribute__((address_space(1))) void*)g,
      (__attribute__((address_space(3))) void*)l, 16, 0, 0);
}

// ---------------- prep kernels ----------------

// f32 [R][C] -> bf16 [C][R]  (tiled transpose+convert)
__global__ void k_transpose_cvt(const float* __restrict__ in, u16* __restrict__ out,
                                int R, int C) {
  __shared__ float tile[32][33];
  int bc = blockIdx.x * 32, br = blockIdx.y * 32;
  int tx = threadIdx.x & 31, ty0 = threadIdx.x >> 5;  // 256 thr: 32 x 8
#pragma unroll
  for (int i = 0; i < 4; ++i) {
    int ty = ty0 + i * 8;
    tile[ty][tx] = in[(size_t)(br + ty) * C + bc + tx];
  }
  __syncthreads();
#pragma unroll
  for (int i = 0; i < 4; ++i) {
    int ty = ty0 + i * 8;
    out[(size_t)(bc + ty) * R + br + tx] = f2bf(tile[tx][ty]);
  }
}

// elementwise f32 -> bf16 (vector 4)
__global__ void k_cvt_bf16(const float* __restrict__ in, u16* __restrict__ out, int n4) {
  int i = blockIdx.x * blockDim.x + threadIdx.x;
  int stride = gridDim.x * blockDim.x;
  for (; i < n4; i += stride) {
    float4 v = ((const float4*)in)[i];
    ushort4 o;
    o.x = f2bf(v.x); o.y = f2bf(v.y); o.z = f2bf(v.z); o.w = f2bf(v.w);
    ((ushort4*)out)[i] = o;
  }
}

// gather embedding rows -> Xbf, row r = t*32+b  (token = input[b*256+t])
__global__ void k_gather_x(const float* __restrict__ emb, const int* __restrict__ inp,
                           u16* __restrict__ Xbf) {
  int row = blockIdx.x;
  int t = row >> 5, b = row & 31;
  int tok = inp[b * T + t];
  const float4* src = (const float4*)(emb + (size_t)tok * H);
  ushort4* dst = (ushort4*)(Xbf + (size_t)row * H);
  float4 v = src[threadIdx.x];
  ushort4 o;
  o.x = f2bf(v.x); o.y = f2bf(v.y); o.z = f2bf(v.z); o.w = f2bf(v.w);
  dst[threadIdx.x] = o;
}

__global__ void k_zero(unsigned int* __restrict__ p, int nwords) {
  int i = blockIdx.x * blockDim.x + threadIdx.x;
  int stride = gridDim.x * blockDim.x;
  for (; i < nwords; i += stride) p[i] = 0u;
}

// ---------------- 128x128 bf16 MFMA GEMM (m97 structure) ----------------
// C[M,N](f32) = A[M,K](bf16,row-major) * Bt[N,K](bf16,row-major)^T + bias[N]
// SM_EPI: also write per-(row, colblock) online softmax partials (max, sumexp)
template <bool SM_EPI>
__global__ __launch_bounds__(256)
void k_gemm(const u16* __restrict__ A, int lda,
            const u16* __restrict__ Bt, int ldb,
            float* __restrict__ C, int ldc,
            const float* __restrict__ bias, int K,
            float* __restrict__ pmax, float* __restrict__ psum, int nch) {
  __shared__ alignas(16) u16 ldsA[128 * 32];
  __shared__ alignas(16) u16 ldsB[128 * 32];
  __shared__ float2 red[128][2];

  int tid = threadIdx.x, lane = tid & 63, w = tid >> 6;
  int row0 = blockIdx.y * 128, col0 = blockIdx.x * 128;
  int wr = w >> 1, wc = w & 1;
  int c15 = lane & 15, q4 = lane >> 4;

  // staging source pointers: call j covers LDS elems [(j*4+w)*512 + lane*8]
  const u16* ag[2]; const u16* bg[2];
#pragma unroll
  for (int j = 0; j < 2; ++j) {
    int r = (j * 4 + w) * 16 + (lane >> 2);
    int k = (lane & 3) * 8;
    ag[j] = A + (size_t)(row0 + r) * lda + k;
    bg[j] = Bt + (size_t)(col0 + r) * ldb + k;
  }
  u16* lA0 = ldsA + (size_t)(0 + w) * 512;
  u16* lA1 = ldsA + (size_t)(4 + w) * 512;
  u16* lB0 = ldsB + (size_t)(0 + w) * 512;
  u16* lB1 = ldsB + (size_t)(4 + w) * 512;

  f32x4 acc[4][4];
#pragma unroll
  for (int m = 0; m < 4; ++m)
#pragma unroll
    for (int n = 0; n < 4; ++n) acc[m][n] = (f32x4){0.f, 0.f, 0.f, 0.f};

  int nk = K >> 5;
  for (int kk = 0; kk < nk; ++kk) {
    int kb = kk * 32;
    gload_lds16(ag[0] + kb, lA0);
    gload_lds16(ag[1] + kb, lA1);
    gload_lds16(bg[0] + kb, lB0);
    gload_lds16(bg[1] + kb, lB1);
    __syncthreads();  // drains vmcnt -> staged data visible

    short8 af[4], bfr[4];
#pragma unroll
    for (int m = 0; m < 4; ++m)
      af[m] = *(const short8*)(ldsA + (wr * 64 + m * 16 + c15) * 32 + q4 * 8);
#pragma unroll
    for (int n = 0; n < 4; ++n)
      bfr[n] = *(const short8*)(ldsB + (wc * 64 + n * 16 + c15) * 32 + q4 * 8);
#pragma unroll
    for (int m = 0; m < 4; ++m)
#pragma unroll
      for (int n = 0; n < 4; ++n)
        acc[m][n] = __builtin_amdgcn_mfma_f32_16x16x32_bf16(af[m], bfr[n], acc[m][n], 0, 0, 0);
    __syncthreads();  // all reads done before next overwrite
  }

  float bias_n[4];
#pragma unroll
  for (int n = 0; n < 4; ++n) bias_n[n] = bias[col0 + wc * 64 + n * 16 + c15];

  // C layout: col = lane&15, row = (lane>>4)*4 + reg  [m89]
#pragma unroll
  for (int m = 0; m < 4; ++m) {
#pragma unroll
    for (int jr = 0; jr < 4; ++jr) {
      int r_g = row0 + wr * 64 + m * 16 + q4 * 4 + jr;
      float v[4];
#pragma unroll
      for (int n = 0; n < 4; ++n) {
        int c_g = col0 + wc * 64 + n * 16 + c15;
        float val = acc[m][n][jr] + bias_n[n];
        C[(size_t)r_g * ldc + c_g] = val;
        v[n] = val;
      }
      if (SM_EPI) {
        float mx = fmaxf(fmaxf(v[0], v[1]), fmaxf(v[2], v[3]));
        float s = __expf(v[0] - mx) + __expf(v[1] - mx) + __expf(v[2] - mx) + __expf(v[3] - mx);
#pragma unroll
        for (int d = 1; d < 16; d <<= 1) {  // reduce over the 16 lanes sharing this row
          float mo = __shfl_xor(mx, d, 64);
          float so = __shfl_xor(s, d, 64);
          float M2 = fmaxf(mx, mo);
          s = s * __expf(mx - M2) + so * __expf(mo - M2);
          mx = M2;
        }
        if (c15 == 0) red[wr * 64 + m * 16 + q4 * 4 + jr][wc] = make_float2(mx, s);
      }
    }
  }
  if (SM_EPI) {
    __syncthreads();
    if (tid < 128) {
      float2 a = red[tid][0], b2 = red[tid][1];
      float M2 = fmaxf(a.x, b2.x);
      float S = a.y * __expf(a.x - M2) + b2.y * __expf(b2.x - M2);
      pmax[(size_t)(row0 + tid) * nch + blockIdx.x] = M2;
      psum[(size_t)(row0 + tid) * nch + blockIdx.x] = S;
    }
  }
}

// ---------------- one LSTM step, one layer ----------------
// z[b][g] = zb + sum_k Arow[b][k] * WT[g][koff+k];  gates i,j,f,o; 64 WGs x 256 thr.
// WG owns 16 hidden units; computes the 4 gate cols for them so activation fuses.
template <int KH>
__global__ __launch_bounds__(256)
void k_lstm_step(const u16* __restrict__ A1,  // rows[32] stride 2048, k in [0,1024)
                 const u16* __restrict__ A2,  // k in [1024,2048) (layer1)
                 const u16* __restrict__ WT,  // [4096][2048] bf16
                 int koff,
                 const float* __restrict__ zb, int zb_stride,  // stride0 => broadcast bias
                 const float* __restrict__ c_in, float* __restrict__ c_out,
                 u16* __restrict__ hout,                        // hout[b*2048+u]
                 u16* __restrict__ hout2, int h2stride, int t_unused) {
  __shared__ float red[4][2][4][16][16];  // [wave][rowtile][gate][row][col] 32KB
  int tid = threadIdx.x, lane = tid & 63, w = tid >> 6;
  int wg = blockIdx.x;                    // unit group: units wg*16..wg*16+15
  int c15 = lane & 15, q4 = lane >> 4;
  constexpr int KS = KH / 4;              // per-wave K slice
  constexpr int NIT = KS / 32;

  const u16* bp[4];
#pragma unroll
  for (int q = 0; q < 4; ++q)
    bp[q] = WT + (size_t)(q * 1024 + wg * 16 + c15) * 2048 + koff + q4 * 8;

  f32x4 acc[2][4];
#pragma unroll
  for (int rt = 0; rt < 2; ++rt)
#pragma unroll
    for (int q = 0; q < 4; ++q) acc[rt][q] = (f32x4){0.f, 0.f, 0.f, 0.f};

  int k0 = w * KS;
#pragma unroll 4
  for (int it = 0; it < NIT; ++it) {
    int kbase = k0 + it * 32;
    int k = kbase + q4 * 8;
    short8 a[2];
#pragma unroll
    for (int rt = 0; rt < 2; ++rt) {
      int r = rt * 16 + c15;
      const u16* ap = (KH == 1024 || k < 1024) ? (A1 + r * 2048 + k)
                                               : (A2 + r * 2048 + (k - 1024));
      a[rt] = *(const short8*)ap;
    }
#pragma unroll
    for (int q = 0; q < 4; ++q) {
      short8 b8 = *(const short8*)(bp[q] + kbase);
#pragma unroll
      for (int rt = 0; rt < 2; ++rt)
        acc[rt][q] = __builtin_amdgcn_mfma_f32_16x16x32_bf16(a[rt], b8, acc[rt][q], 0, 0, 0);
    }
  }

#pragma unroll
  for (int rt = 0; rt < 2; ++rt)
#pragma unroll
    for (int q = 0; q < 4; ++q)
#pragma unroll
      for (int jr = 0; jr < 4; ++jr)
        red[w][rt][q][q4 * 4 + jr][c15] = acc[rt][q][jr];
  __syncthreads();

  // 512 (b,unit) pairs, 2 per thread
#pragma unroll
  for (int pp = 0; pp < 2; ++pp) {
    int p = tid + pp * 256;
    int b = p >> 4, uu = p & 15;
    int rt = b >> 4, rr = b & 15;
    float z[4];
#pragma unroll
    for (int q = 0; q < 4; ++q) {
      float s = red[0][rt][q][rr][uu] + red[1][rt][q][rr][uu] +
                red[2][rt][q][rr][uu] + red[3][rt][q][rr][uu];
      int g = q * 1024 + wg * 16 + uu;
      s += zb_stride ? zb[b * zb_stride + g] : zb[g];
      z[q] = s;
    }
    int u = wg * 16 + uu;
    float c_old = c_in[b * 1024 + u];
    float gi = sigm(z[0]);
    float gj = tanhf(z[1]);
    float gf = sigm(z[2] + 1.f);   // forget_bias = 1.0
    float go = sigm(z[3]);
    float c2 = c_old * gf + gi * gj;
    float h2 = go * tanhf(c2);
    c_out[b * 1024 + u] = c2;
    hout[b * 2048 + u] = f2bf(h2);
    if (hout2) hout2[(size_t)b * h2stride + u] = f2bf(h2);
  }
}

// ---------------- softmax finalize ----------------
__global__ void k_rowfin(const float* __restrict__ pmax, const float* __restrict__ psum,
                         const float* __restrict__ Cl, const int* __restrict__ targets,
                         float* __restrict__ loss) {
  int row = blockIdx.x;
  int tid = threadIdx.x, lane = tid & 63, w = tid >> 6;
  float mx = -1e30f, s = 0.f;
  if (tid < NCH) { mx = pmax[(size_t)row * NCH + tid]; s = psum[(size_t)row * NCH + tid]; }
#pragma unroll
  for (int d = 1; d < 64; d <<= 1) {
    float mo = __shfl_xor(mx, d, 64);
    float so = __shfl_xor(s, d, 64);
    float M2 = fmaxf(mx, mo);
    s = s * __expf(mx - M2) + so * __expf(mo - M2);
    mx = M2;
  }
  __shared__ float2 wred[4];
  if (lane == 0) wred[w] = make_float2(mx, s);
  __syncthreads();
  if (tid == 0) {
    float M = wred[0].x, S = wred[0].y;
#pragma unroll
    for (int i = 1; i < 4; ++i) {
      float M2 = fmaxf(M, wred[i].x);
      S = S * __expf(M - M2) + wred[i].y * __expf(wred[i].x - M2);
      M = M2;
    }
    float logZ = M + logf(S);
    int tgt = targets[row];  // row = b*T+t matches targets flat layout
    float xt = Cl[(size_t)row * V + tgt];
    loss[row] = logZ - xt;
  }
}

__global__ void k_cost(const float* __restrict__ loss, float* __restrict__ out) {
  int tid = threadIdx.x, lane = tid & 63, w = tid >> 6;
  float s = 0.f;
  for (int i = tid; i < BT; i += 256) s += loss[i];
#pragma unroll
  for (int d = 1; d < 64; d <<= 1) s += __shfl_xor(s, d, 64);
  __shared__ float ws4[4];
  if (lane == 0) ws4[w] = s;
  __syncthreads();
  if (tid == 0) out[0] = (ws4[0] + ws4[1] + ws4[2] + ws4[3]) * (1.0f / B);
}

// ---------------- host ----------------
extern "C" void kernel_launch(void* const* d_in, const int* in_sizes, int n_in,
                              void* d_out, int out_size, void* d_ws, size_t ws_size,
                              hipStream_t stream) {
  const int*   input_data = (const int*)d_in[0];
  const int*   targets    = (const int*)d_in[1];
  const float* emb        = (const float*)d_in[2];
  const float* softmax_b  = (const float*)d_in[3];
  const float* W0         = (const float*)d_in[4];
  const float* b0         = (const float*)d_in[5];
  const float* W1         = (const float*)d_in[6];
  const float* b1         = (const float*)d_in[7];
  float* out = (float*)d_out;
  char*  ws  = (char*)d_ws;

  u16*   W0T  = (u16*)(ws + OFF_W0T);
  u16*   W1T  = (u16*)(ws + OFF_W1T);
  u16*   Ebf  = (u16*)(ws + OFF_EBF);
  u16*   Xbf  = (u16*)(ws + OFF_XBF);
  float* xp0  = (float*)(ws + OFF_XP0);
  u16*   H1bf = (u16*)(ws + OFF_H1);
  u16*   hbuf = (u16*)(ws + OFF_HBUF);
  float* c0   = (float*)(ws + OFF_C0);
  float* c1   = (float*)(ws + OFF_C1);
  float* pmax = (float*)(ws + OFF_PMAX);
  float* psum = (float*)(ws + OFF_PSUM);
  float* lossb= (float*)(ws + OFF_LOSS);

  // prep: weight transposes (bf16), embedding convert, X gather, state zero
  k_transpose_cvt<<<dim3(G / 32, 2048 / 32), 256, 0, stream>>>(W0, W0T, 2048, G);
  k_transpose_cvt<<<dim3(G / 32, 2048 / 32), 256, 0, stream>>>(W1, W1T, 2048, G);
  k_cvt_bf16<<<2048, 256, 0, stream>>>(emb, Ebf, V * H / 4);
  k_gather_x<<<BT, 256, 0, stream>>>(emb, input_data, Xbf);
  k_zero<<<128, 256, 0, stream>>>((unsigned int*)(ws + OFF_HBUF),
                                  (int)((2 * 32 * 2048 * 2 + 2 * 32 * 1024 * 4) / 4));

  // xpart0 = X @ W0[0:1024,:] + b0   (f32 out, row = t*32+b)
  k_gemm<false><<<dim3(G / 128, BT / 128), 256, 0, stream>>>(
      Xbf, H, W0T, 2048, xp0, G, b0, H, nullptr, nullptr, 0);

  // sequential LSTM: 256 steps x 2 layers
  for (int t = 0; t < T; ++t) {
    int cur = t & 1, nxt = cur ^ 1;
    u16* hc = hbuf + (size_t)cur * 32 * 2048;
    u16* hn = hbuf + (size_t)nxt * 32 * 2048;
    // layer0: z = xpart0[t] + h0_prev @ Wh0 ; Wh0 = W0T[:,1024:2048]
    k_lstm_step<1024><<<64, 256, 0, stream>>>(
        hc, nullptr, W0T, 1024,
        xp0 + (size_t)t * 32 * G, G,
        c0, c0, hn, nullptr, 0, t);
    // layer1: z = [h0_t, h1_prev] @ W1 + b1
    k_lstm_step<2048><<<64, 256, 0, stream>>>(
        hn, hc + 1024, W1T, 0,
        b1, 0,
        c1, c1, hn + 1024, H1bf + (size_t)t * H, T * H, t);
  }

  // logits = H1 @ E^T + softmax_b, fused online-softmax partials
  k_gemm<true><<<dim3(V / 128, BT / 128), 256, 0, stream>>>(
      H1bf, H, Ebf, H, out, V, softmax_b, H, pmax, psum, NCH);

  // per-row logZ + NLL, then cost = sum/B appended after logits
  k_rowfin<<<BT, 256, 0, stream>>>(pmax, psum, out, targets, lossb);
  k_cost<<<1, 256, 0, stream>>>(lossb, out + (size_t)BT * V);
}

// Round 2
// 6998.983 us; speedup vs baseline: 1.3986x; 1.3986x over previous
//
#include <hip/hip_runtime.h>
#include <hip/hip_bf16.h>

#define DEV static __device__ __forceinline__

typedef unsigned short u16;
typedef unsigned long long u64;
typedef __attribute__((ext_vector_type(8))) short short8;   // 8 bf16 (4 VGPRs) MFMA frag
typedef __attribute__((ext_vector_type(4))) float f32x4;    // MFMA accumulator

constexpr int V = 32000, H = 1024, B = 32, T = 256;
constexpr int BT = B * T;       // 8192 rows
constexpr int G  = 4 * H;       // 4096 gates
constexpr int NCH = V / 128;    // 250 col-chunks for softmax partials
constexpr int NWG = 128;        // persistent LSTM blocks (64 L0 + 64 L1)

// ---------------- workspace layout (bytes) ----------------
constexpr size_t SZ_WT    = (size_t)G * 2048 * 2;            // [4096][2048] bf16
constexpr size_t OFF_W0T  = 0;
constexpr size_t OFF_W1T  = OFF_W0T + SZ_WT;
constexpr size_t OFF_EBF  = OFF_W1T + SZ_WT;                 // [32000][1024] bf16
constexpr size_t OFF_XBF  = OFF_EBF + (size_t)V * H * 2;     // [8192][1024] bf16 (row = t*32+b)
constexpr size_t OFF_XP0  = OFF_XBF + (size_t)BT * H * 2;    // [8192][4096] f32 (row = t*32+b)
constexpr size_t OFF_H1   = OFF_XP0 + (size_t)BT * G * 4;    // [8192][1024] bf16 (row = b*256+t)
constexpr size_t OFF_HBUF = OFF_H1 + (size_t)BT * H * 2;     // [2][32][2048] bf16 (h0|h1 concat)
constexpr size_t OFF_SYNC = OFF_HBUF + (size_t)2 * 32 * 2048 * 2;   // barrier words (256B)
constexpr size_t OFF_PMAX = OFF_SYNC + (size_t)2 * 32 * 1024 * 4;   // [8192][250] f32
constexpr size_t OFF_PSUM = OFF_PMAX + (size_t)BT * NCH * 4;
constexpr size_t OFF_LOSS = OFF_PSUM + (size_t)BT * NCH * 4; // [8192] f32

DEV u16 f2bf(float x) {  // RNE f32 -> bf16 bits
  union { float f; unsigned int u; } v; v.f = x;
  unsigned int r = v.u + 0x7fffu + ((v.u >> 16) & 1u);
  return (u16)(r >> 16);
}
DEV float sigm(float x) { return 1.f / (1.f + expf(-x)); }

DEV void gload_lds16(const u16* g, u16* l) {
  __builtin_amdgcn_global_load_lds(
      (__attribute__((address_space(1))) void*)g,
      (__attribute__((address_space(3))) void*)l, 16, 0, 0);
}

// agent-scope (device-coherent, L1/L2-bypassing) 16B fragment load: 2 x 8B
DEV short8 ld_frag_agent(const u16* p) {
  u64 lo = __hip_atomic_load((u64*)p,       __ATOMIC_RELAXED, __HIP_MEMORY_SCOPE_AGENT);
  u64 hi = __hip_atomic_load((u64*)(p + 4), __ATOMIC_RELAXED, __HIP_MEMORY_SCOPE_AGENT);
  union { u64 q[2]; short8 s; } u;
  u.q[0] = lo; u.q[1] = hi;
  return u.s;
}

// ---------------- prep kernels ----------------

__global__ void k_transpose_cvt(const float* __restrict__ in, u16* __restrict__ out,
                                int R, int C) {
  __shared__ float tile[32][33];
  int bc = blockIdx.x * 32, br = blockIdx.y * 32;
  int tx = threadIdx.x & 31, ty0 = threadIdx.x >> 5;
#pragma unroll
  for (int i = 0; i < 4; ++i) {
    int ty = ty0 + i * 8;
    tile[ty][tx] = in[(size_t)(br + ty) * C + bc + tx];
  }
  __syncthreads();
#pragma unroll
  for (int i = 0; i < 4; ++i) {
    int ty = ty0 + i * 8;
    out[(size_t)(bc + ty) * R + br + tx] = f2bf(tile[tx][ty]);
  }
}

__global__ void k_cvt_bf16(const float* __restrict__ in, u16* __restrict__ out, int n4) {
  int i = blockIdx.x * blockDim.x + threadIdx.x;
  int stride = gridDim.x * blockDim.x;
  for (; i < n4; i += stride) {
    float4 v = ((const float4*)in)[i];
    ushort4 o;
    o.x = f2bf(v.x); o.y = f2bf(v.y); o.z = f2bf(v.z); o.w = f2bf(v.w);
    ((ushort4*)out)[i] = o;
  }
}

__global__ void k_gather_x(const float* __restrict__ emb, const int* __restrict__ inp,
                           u16* __restrict__ Xbf) {
  int row = blockIdx.x;
  int t = row >> 5, b = row & 31;
  int tok = inp[b * T + t];
  const float4* src = (const float4*)(emb + (size_t)tok * H);
  ushort4* dst = (ushort4*)(Xbf + (size_t)row * H);
  float4 v = src[threadIdx.x];
  ushort4 o;
  o.x = f2bf(v.x); o.y = f2bf(v.y); o.z = f2bf(v.z); o.w = f2bf(v.w);
  dst[threadIdx.x] = o;
}

__global__ void k_zero(unsigned int* __restrict__ p, int nwords) {
  int i = blockIdx.x * blockDim.x + threadIdx.x;
  int stride = gridDim.x * blockDim.x;
  for (; i < nwords; i += stride) p[i] = 0u;
}

// ---------------- 128x128 bf16 MFMA GEMM (m97 structure) ----------------
template <bool SM_EPI>
__global__ __launch_bounds__(256)
void k_gemm(const u16* __restrict__ A, int lda,
            const u16* __restrict__ Bt, int ldb,
            float* __restrict__ C, int ldc,
            const float* __restrict__ bias, int K,
            float* __restrict__ pmax, float* __restrict__ psum, int nch) {
  __shared__ alignas(16) u16 ldsA[128 * 32];
  __shared__ alignas(16) u16 ldsB[128 * 32];
  __shared__ float2 red[128][2];

  int tid = threadIdx.x, lane = tid & 63, w = tid >> 6;
  int row0 = blockIdx.y * 128, col0 = blockIdx.x * 128;
  int wr = w >> 1, wc = w & 1;
  int c15 = lane & 15, q4 = lane >> 4;

  const u16* ag[2]; const u16* bg[2];
#pragma unroll
  for (int j = 0; j < 2; ++j) {
    int r = (j * 4 + w) * 16 + (lane >> 2);
    int k = (lane & 3) * 8;
    ag[j] = A + (size_t)(row0 + r) * lda + k;
    bg[j] = Bt + (size_t)(col0 + r) * ldb + k;
  }
  u16* lA0 = ldsA + (size_t)(0 + w) * 512;
  u16* lA1 = ldsA + (size_t)(4 + w) * 512;
  u16* lB0 = ldsB + (size_t)(0 + w) * 512;
  u16* lB1 = ldsB + (size_t)(4 + w) * 512;

  f32x4 acc[4][4];
#pragma unroll
  for (int m = 0; m < 4; ++m)
#pragma unroll
    for (int n = 0; n < 4; ++n) acc[m][n] = (f32x4){0.f, 0.f, 0.f, 0.f};

  int nk = K >> 5;
  for (int kk = 0; kk < nk; ++kk) {
    int kb = kk * 32;
    gload_lds16(ag[0] + kb, lA0);
    gload_lds16(ag[1] + kb, lA1);
    gload_lds16(bg[0] + kb, lB0);
    gload_lds16(bg[1] + kb, lB1);
    __syncthreads();

    short8 af[4], bfr[4];
#pragma unroll
    for (int m = 0; m < 4; ++m)
      af[m] = *(const short8*)(ldsA + (wr * 64 + m * 16 + c15) * 32 + q4 * 8);
#pragma unroll
    for (int n = 0; n < 4; ++n)
      bfr[n] = *(const short8*)(ldsB + (wc * 64 + n * 16 + c15) * 32 + q4 * 8);
#pragma unroll
    for (int m = 0; m < 4; ++m)
#pragma unroll
      for (int n = 0; n < 4; ++n)
        acc[m][n] = __builtin_amdgcn_mfma_f32_16x16x32_bf16(af[m], bfr[n], acc[m][n], 0, 0, 0);
    __syncthreads();
  }

  float bias_n[4];
#pragma unroll
  for (int n = 0; n < 4; ++n) bias_n[n] = bias[col0 + wc * 64 + n * 16 + c15];

#pragma unroll
  for (int m = 0; m < 4; ++m) {
#pragma unroll
    for (int jr = 0; jr < 4; ++jr) {
      int r_g = row0 + wr * 64 + m * 16 + q4 * 4 + jr;
      float v[4];
#pragma unroll
      for (int n = 0; n < 4; ++n) {
        int c_g = col0 + wc * 64 + n * 16 + c15;
        float val = acc[m][n][jr] + bias_n[n];
        C[(size_t)r_g * ldc + c_g] = val;
        v[n] = val;
      }
      if (SM_EPI) {
        float mx = fmaxf(fmaxf(v[0], v[1]), fmaxf(v[2], v[3]));
        float s = __expf(v[0] - mx) + __expf(v[1] - mx) + __expf(v[2] - mx) + __expf(v[3] - mx);
#pragma unroll
        for (int d = 1; d < 16; d <<= 1) {
          float mo = __shfl_xor(mx, d, 64);
          float so = __shfl_xor(s, d, 64);
          float M2 = fmaxf(mx, mo);
          s = s * __expf(mx - M2) + so * __expf(mo - M2);
          mx = M2;
        }
        if (c15 == 0) red[wr * 64 + m * 16 + q4 * 4 + jr][wc] = make_float2(mx, s);
      }
    }
  }
  if (SM_EPI) {
    __syncthreads();
    if (tid < 128) {
      float2 a = red[tid][0], b2 = red[tid][1];
      float M2 = fmaxf(a.x, b2.x);
      float S = a.y * __expf(a.x - M2) + b2.y * __expf(b2.x - M2);
      pmax[(size_t)(row0 + tid) * nch + blockIdx.x] = M2;
      psum[(size_t)(row0 + tid) * nch + blockIdx.x] = S;
    }
  }
}

// ---------------- persistent 2-layer pipelined LSTM ----------------
// 128 blocks: blocks 0..63 = layer0 (units wg*16..+16), blocks 64..127 = layer1.
// Tick t: L0 computes step t (reads h0(t-1)), L1 computes step t-1
// (reads [h0(t-1) | h1(t-2)] = hread rows). One grid barrier per tick.
// h exchanged via agent-scope atomics (L2-bypassing) so weights stay hot in L2.

#define RED(w_, rt_, q_, r_, c_) red[(((((w_)*2 + (rt_)) * 4 + (q_)) * 16 + (r_)) * 16 + (c_))]

template <int KH>
DEV void lstm_tick(const u16* __restrict__ hread,   // [32][2048] bf16
                   const u16* __restrict__ WT, int koffw,
                   const float* __restrict__ zb, int zb_stride,
                   float* __restrict__ c_lds, float* __restrict__ red,
                   u16* __restrict__ hwr_slice,     // hbuf write slice base (stride 2048)
                   u16* __restrict__ h1out, int h1stride, int wgu) {
  int tid = threadIdx.x, lane = tid & 63, w = tid >> 6;
  int c15 = lane & 15, q4 = lane >> 4;
  constexpr int NIT = KH / 128;    // k-steps per wave (wave K-slice / 32)
  int k0 = w * (KH / 4);

  // issue ALL A (h) loads up front: deep vmcnt pipeline, one latency
  short8 afr[NIT][2];
#pragma unroll
  for (int it = 0; it < NIT; ++it) {
    int k = k0 + it * 32 + q4 * 8;
#pragma unroll
    for (int rt = 0; rt < 2; ++rt)
      afr[it][rt] = ld_frag_agent(hread + (size_t)(rt * 16 + c15) * 2048 + k);
  }

  const u16* bp[4];
#pragma unroll
  for (int q = 0; q < 4; ++q)
    bp[q] = WT + (size_t)(q * 1024 + wgu * 16 + c15) * 2048 + koffw + q4 * 8;

  f32x4 acc[2][4];
#pragma unroll
  for (int rt = 0; rt < 2; ++rt)
#pragma unroll
    for (int q = 0; q < 4; ++q) acc[rt][q] = (f32x4){0.f, 0.f, 0.f, 0.f};

#pragma unroll
  for (int it = 0; it < NIT; ++it) {
    int kbase = k0 + it * 32;
#pragma unroll
    for (int q = 0; q < 4; ++q) {
      short8 b8 = *(const short8*)(bp[q] + kbase);   // weights: normal load, L2-resident
#pragma unroll
      for (int rt = 0; rt < 2; ++rt)
        acc[rt][q] = __builtin_amdgcn_mfma_f32_16x16x32_bf16(afr[it][rt], b8, acc[rt][q], 0, 0, 0);
    }
  }

  // cross-wave K reduction via LDS
#pragma unroll
  for (int rt = 0; rt < 2; ++rt)
#pragma unroll
    for (int q = 0; q < 4; ++q)
#pragma unroll
      for (int jr = 0; jr < 4; ++jr)
        RED(w, rt, q, q4 * 4 + jr, c15) = acc[rt][q][jr];
  __syncthreads();

  // epilogue: 256 threads x 2 adjacent units
  int b = tid >> 3;            // 0..31
  int j2 = (tid & 7) * 2;      // 0..14 even
  int rt = b >> 4, rr = b & 15;
  float hv[2];
#pragma unroll
  for (int e = 0; e < 2; ++e) {
    int uu = j2 + e;
    float z[4];
#pragma unroll
    for (int q = 0; q < 4; ++q) {
      float s = RED(0, rt, q, rr, uu) + RED(1, rt, q, rr, uu) +
                RED(2, rt, q, rr, uu) + RED(3, rt, q, rr, uu);
      int g = q * 1024 + wgu * 16 + uu;
      s += zb_stride ? zb[(size_t)b * zb_stride + g] : zb[g];
      z[q] = s;
    }
    float c_old = c_lds[b * 16 + uu];
    float gi = sigm(z[0]);
    float gj = tanhf(z[1]);
    float gf = sigm(z[2] + 1.f);   // forget_bias = 1.0
    float go = sigm(z[3]);
    float c2 = c_old * gf + gi * gj;
    hv[e] = go * tanhf(c2);
    c_lds[b * 16 + uu] = c2;       // c-state persists in LDS across ticks
  }
  unsigned int pack = (unsigned int)f2bf(hv[0]) | ((unsigned int)f2bf(hv[1]) << 16);
  __hip_atomic_store((unsigned int*)(hwr_slice + (size_t)b * 2048 + j2), pack,
                     __ATOMIC_RELAXED, __HIP_MEMORY_SCOPE_AGENT);
  if (h1out)
    *(unsigned int*)(h1out + (size_t)b * h1stride + j2) = pack;  // H1 output (normal store)
}

__global__ __launch_bounds__(256, 1)
void k_lstm_persistent(const u16* __restrict__ W0T, const u16* __restrict__ W1T,
                       const float* __restrict__ xp0, const float* __restrict__ b1,
                       u16* __restrict__ hbuf, u16* __restrict__ H1bf,
                       int* __restrict__ sync) {
  __shared__ float red[4 * 2 * 4 * 16 * 16];   // 8KB... (4 waves x 2 x 4 x 16 x 16) = 32KB
  __shared__ float c_lds[512];

  int tid = threadIdx.x;
  int wg = blockIdx.x;
  bool isL0 = wg < 64;
  int wgu = isL0 ? wg : wg - 64;

  c_lds[tid] = 0.f;
  c_lds[tid + 256] = 0.f;
  __syncthreads();

  for (int tick = 0; tick <= T; ++tick) {
    const u16* hread = hbuf + (size_t)((tick + 1) & 1) * (32 * 2048);  // parity (tick-1)&1
    u16* hwr = hbuf + (size_t)(tick & 1) * (32 * 2048);

    if (isL0) {
      if (tick < T)
        lstm_tick<1024>(hread, W0T, 1024,
                        xp0 + (size_t)tick * 32 * G, G,
                        c_lds, red, hwr + wgu * 16, nullptr, 0, wgu);
    } else {
      if (tick >= 1)
        lstm_tick<2048>(hread, W1T, 0,
                        b1, 0,
                        c_lds, red, hwr + 1024 + wgu * 16,
                        H1bf + (size_t)(tick - 1) * H + wgu * 16, T * H, wgu);
    }

    // grid barrier: __syncthreads drains vmcnt (h stores visible at coherence
    // point, agent scope) before the arrive-add; monotonic counter + gen word.
    __syncthreads();
    if (tid == 0) {
      int old = atomicAdd(sync, 1);                 // device-scope by default
      if (old == (tick + 1) * NWG - 1)
        __hip_atomic_store(sync + 16, tick + 1, __ATOMIC_RELAXED, __HIP_MEMORY_SCOPE_AGENT);
      while (__hip_atomic_load(sync + 16, __ATOMIC_RELAXED, __HIP_MEMORY_SCOPE_AGENT) < tick + 1)
        __builtin_amdgcn_s_sleep(2);
    }
    __builtin_amdgcn_sched_barrier(0);
    __syncthreads();
  }
}

// ---------------- softmax finalize ----------------
__global__ void k_rowfin(const float* __restrict__ pmax, const float* __restrict__ psum,
                         const float* __restrict__ Cl, const int* __restrict__ targets,
                         float* __restrict__ loss) {
  int row = blockIdx.x;
  int tid = threadIdx.x, lane = tid & 63, w = tid >> 6;
  float mx = -1e30f, s = 0.f;
  if (tid < NCH) { mx = pmax[(size_t)row * NCH + tid]; s = psum[(size_t)row * NCH + tid]; }
#pragma unroll
  for (int d = 1; d < 64; d <<= 1) {
    float mo = __shfl_xor(mx, d, 64);
    float so = __shfl_xor(s, d, 64);
    float M2 = fmaxf(mx, mo);
    s = s * __expf(mx - M2) + so * __expf(mo - M2);
    mx = M2;
  }
  __shared__ float2 wred[4];
  if (lane == 0) wred[w] = make_float2(mx, s);
  __syncthreads();
  if (tid == 0) {
    float M = wred[0].x, S = wred[0].y;
#pragma unroll
    for (int i = 1; i < 4; ++i) {
      float M2 = fmaxf(M, wred[i].x);
      S = S * __expf(M - M2) + wred[i].y * __expf(wred[i].x - M2);
      M = M2;
    }
    float logZ = M + logf(S);
    int tgt = targets[row];
    float xt = Cl[(size_t)row * V + tgt];
    loss[row] = logZ - xt;
  }
}

__global__ void k_cost(const float* __restrict__ loss, float* __restrict__ out) {
  int tid = threadIdx.x, lane = tid & 63, w = tid >> 6;
  float s = 0.f;
  for (int i = tid; i < BT; i += 256) s += loss[i];
#pragma unroll
  for (int d = 1; d < 64; d <<= 1) s += __shfl_xor(s, d, 64);
  __shared__ float ws4[4];
  if (lane == 0) ws4[w] = s;
  __syncthreads();
  if (tid == 0) out[0] = (ws4[0] + ws4[1] + ws4[2] + ws4[3]) * (1.0f / B);
}

// ---------------- host ----------------
extern "C" void kernel_launch(void* const* d_in, const int* in_sizes, int n_in,
                              void* d_out, int out_size, void* d_ws, size_t ws_size,
                              hipStream_t stream) {
  const int*   input_data = (const int*)d_in[0];
  const int*   targets    = (const int*)d_in[1];
  const float* emb        = (const float*)d_in[2];
  const float* softmax_b  = (const float*)d_in[3];
  const float* W0         = (const float*)d_in[4];
  const float* b0         = (const float*)d_in[5];
  const float* W1         = (const float*)d_in[6];
  const float* b1         = (const float*)d_in[7];
  float* out = (float*)d_out;
  char*  ws  = (char*)d_ws;

  u16*   W0T  = (u16*)(ws + OFF_W0T);
  u16*   W1T  = (u16*)(ws + OFF_W1T);
  u16*   Ebf  = (u16*)(ws + OFF_EBF);
  u16*   Xbf  = (u16*)(ws + OFF_XBF);
  float* xp0  = (float*)(ws + OFF_XP0);
  u16*   H1bf = (u16*)(ws + OFF_H1);
  u16*   hbuf = (u16*)(ws + OFF_HBUF);
  int*   sync = (int*)(ws + OFF_SYNC);
  float* pmax = (float*)(ws + OFF_PMAX);
  float* psum = (float*)(ws + OFF_PSUM);
  float* lossb= (float*)(ws + OFF_LOSS);

  // prep: weight transposes (bf16), embedding convert, X gather, h/sync zero
  k_transpose_cvt<<<dim3(G / 32, 2048 / 32), 256, 0, stream>>>(W0, W0T, 2048, G);
  k_transpose_cvt<<<dim3(G / 32, 2048 / 32), 256, 0, stream>>>(W1, W1T, 2048, G);
  k_cvt_bf16<<<2048, 256, 0, stream>>>(emb, Ebf, V * H / 4);
  k_gather_x<<<BT, 256, 0, stream>>>(emb, input_data, Xbf);
  k_zero<<<64, 256, 0, stream>>>((unsigned int*)(ws + OFF_HBUF),
                                 (int)((2 * 32 * 2048 * 2 + 256) / 4));

  // xpart0 = X @ W0[0:1024,:] + b0   (f32 out, row = t*32+b)
  k_gemm<false><<<dim3(G / 128, BT / 128), 256, 0, stream>>>(
      Xbf, H, W0T, 2048, xp0, G, b0, H, nullptr, nullptr, 0);

  // persistent pipelined LSTM: 257 ticks, 1 grid barrier each
  k_lstm_persistent<<<dim3(NWG), dim3(256), 0, stream>>>(
      W0T, W1T, xp0, b1, hbuf, H1bf, sync);

  // logits = H1 @ E^T + softmax_b, fused online-softmax partials
  k_gemm<true><<<dim3(V / 128, BT / 128), 256, 0, stream>>>(
      H1bf, H, Ebf, H, out, V, softmax_b, H, pmax, psum, NCH);

  // per-row logZ + NLL, then cost = sum/B appended after logits
  k_rowfin<<<BT, 256, 0, stream>>>(pmax, psum, out, targets, lossb);
  k_cost<<<1, 256, 0, stream>>>(lossb, out + (size_t)BT * V);
}

// Round 3
// 5000.669 us; speedup vs baseline: 1.9575x; 1.3996x over previous
//
#include <hip/hip_runtime.h>
#include <hip/hip_bf16.h>

#define DEV static __device__ __forceinline__

typedef unsigned short u16;
typedef unsigned long long u64;
typedef __attribute__((ext_vector_type(8))) short short8;   // 8 bf16 (4 VGPRs) MFMA frag
typedef __attribute__((ext_vector_type(4))) float f32x4;    // MFMA accumulator

constexpr int V = 32000, H = 1024, B = 32, T = 256;
constexpr int BT = B * T;       // 8192 rows
constexpr int G  = 4 * H;       // 4096 gates
constexpr int NCH = V / 128;    // 250 col-chunks for softmax partials
constexpr int NWG = 128;        // persistent LSTM blocks (64 L0 + 64 L1)
constexpr int RSTRIDE = 32 * 2048 + 2048;  // u16 per h-buffer (132KB incl 4KB pad)

// ---------------- workspace layout (bytes) ----------------
constexpr size_t SZ_WT    = (size_t)G * 2048 * 2;            // [4096][2048] bf16
constexpr size_t OFF_W0T  = 0;
constexpr size_t OFF_W1T  = OFF_W0T + SZ_WT;
constexpr size_t OFF_EBF  = OFF_W1T + SZ_WT;                 // [32000][1024] bf16
constexpr size_t OFF_XBF  = OFF_EBF + (size_t)V * H * 2;     // [8192][1024] bf16 (row = t*32+b)
constexpr size_t OFF_XP0  = OFF_XBF + (size_t)BT * H * 2;    // [8192][4096] f32 (row = t*32+b)
constexpr size_t OFF_H1   = OFF_XP0 + (size_t)BT * G * 4;    // [8192][1024] bf16 (row = b*256+t)
constexpr size_t OFF_HSEQ = OFF_H1 + (size_t)BT * H * 2;     // R[0..T+1], write-once per tick
constexpr size_t SZ_HSEQ  = (size_t)(T + 2) * RSTRIDE * 2;
constexpr size_t OFF_SYNC = OFF_HSEQ + SZ_HSEQ;              // barrier counters (4KB)
constexpr size_t OFF_PMAX = OFF_SYNC + 4096;                 // [8192][250] f32
constexpr size_t OFF_PSUM = OFF_PMAX + (size_t)BT * NCH * 4;
constexpr size_t OFF_LOSS = OFF_PSUM + (size_t)BT * NCH * 4; // [8192] f32

DEV u16 f2bf(float x) {  // RNE f32 -> bf16 bits
  union { float f; unsigned int u; } v; v.f = x;
  unsigned int r = v.u + 0x7fffu + ((v.u >> 16) & 1u);
  return (u16)(r >> 16);
}
DEV float sigm(float x) { return 1.f / (1.f + expf(-x)); }

DEV void gload_lds16(const u16* g, u16* l) {
  __builtin_amdgcn_global_load_lds(
      (__attribute__((address_space(1))) void*)g,
      (__attribute__((address_space(3))) void*)l, 16, 0, 0);
}

// ---------------- prep kernels ----------------

__global__ void k_transpose_cvt(const float* __restrict__ in, u16* __restrict__ out,
                                int R, int C) {
  __shared__ float tile[32][33];
  int bc = blockIdx.x * 32, br = blockIdx.y * 32;
  int tx = threadIdx.x & 31, ty0 = threadIdx.x >> 5;
#pragma unroll
  for (int i = 0; i < 4; ++i) {
    int ty = ty0 + i * 8;
    tile[ty][tx] = in[(size_t)(br + ty) * C + bc + tx];
  }
  __syncthreads();
#pragma unroll
  for (int i = 0; i < 4; ++i) {
    int ty = ty0 + i * 8;
    out[(size_t)(bc + ty) * R + br + tx] = f2bf(tile[tx][ty]);
  }
}

__global__ void k_cvt_bf16(const float* __restrict__ in, u16* __restrict__ out, int n4) {
  int i = blockIdx.x * blockDim.x + threadIdx.x;
  int stride = gridDim.x * blockDim.x;
  for (; i < n4; i += stride) {
    float4 v = ((const float4*)in)[i];
    ushort4 o;
    o.x = f2bf(v.x); o.y = f2bf(v.y); o.z = f2bf(v.z); o.w = f2bf(v.w);
    ((ushort4*)out)[i] = o;
  }
}

__global__ void k_gather_x(const float* __restrict__ emb, const int* __restrict__ inp,
                           u16* __restrict__ Xbf) {
  int row = blockIdx.x;
  int t = row >> 5, b = row & 31;
  int tok = inp[b * T + t];
  const float4* src = (const float4*)(emb + (size_t)tok * H);
  ushort4* dst = (ushort4*)(Xbf + (size_t)row * H);
  float4 v = src[threadIdx.x];
  ushort4 o;
  o.x = f2bf(v.x); o.y = f2bf(v.y); o.z = f2bf(v.z); o.w = f2bf(v.w);
  dst[threadIdx.x] = o;
}

__global__ void k_zero(unsigned int* __restrict__ p, int nwords) {
  int i = blockIdx.x * blockDim.x + threadIdx.x;
  int stride = gridDim.x * blockDim.x;
  for (; i < nwords; i += stride) p[i] = 0u;
}

// ---------------- 128x128 bf16 MFMA GEMM (m97 structure) ----------------
template <bool SM_EPI>
__global__ __launch_bounds__(256)
void k_gemm(const u16* __restrict__ A, int lda,
            const u16* __restrict__ Bt, int ldb,
            float* __restrict__ C, int ldc,
            const float* __restrict__ bias, int K,
            float* __restrict__ pmax, float* __restrict__ psum, int nch) {
  __shared__ alignas(16) u16 ldsA[128 * 32];
  __shared__ alignas(16) u16 ldsB[128 * 32];
  __shared__ float2 red[128][2];

  int tid = threadIdx.x, lane = tid & 63, w = tid >> 6;
  int row0 = blockIdx.y * 128, col0 = blockIdx.x * 128;
  int wr = w >> 1, wc = w & 1;
  int c15 = lane & 15, q4 = lane >> 4;

  const u16* ag[2]; const u16* bg[2];
#pragma unroll
  for (int j = 0; j < 2; ++j) {
    int r = (j * 4 + w) * 16 + (lane >> 2);
    int k = (lane & 3) * 8;
    ag[j] = A + (size_t)(row0 + r) * lda + k;
    bg[j] = Bt + (size_t)(col0 + r) * ldb + k;
  }
  u16* lA0 = ldsA + (size_t)(0 + w) * 512;
  u16* lA1 = ldsA + (size_t)(4 + w) * 512;
  u16* lB0 = ldsB + (size_t)(0 + w) * 512;
  u16* lB1 = ldsB + (size_t)(4 + w) * 512;

  f32x4 acc[4][4];
#pragma unroll
  for (int m = 0; m < 4; ++m)
#pragma unroll
    for (int n = 0; n < 4; ++n) acc[m][n] = (f32x4){0.f, 0.f, 0.f, 0.f};

  int nk = K >> 5;
  for (int kk = 0; kk < nk; ++kk) {
    int kb = kk * 32;
    gload_lds16(ag[0] + kb, lA0);
    gload_lds16(ag[1] + kb, lA1);
    gload_lds16(bg[0] + kb, lB0);
    gload_lds16(bg[1] + kb, lB1);
    __syncthreads();

    short8 af[4], bfr[4];
#pragma unroll
    for (int m = 0; m < 4; ++m)
      af[m] = *(const short8*)(ldsA + (wr * 64 + m * 16 + c15) * 32 + q4 * 8);
#pragma unroll
    for (int n = 0; n < 4; ++n)
      bfr[n] = *(const short8*)(ldsB + (wc * 64 + n * 16 + c15) * 32 + q4 * 8);
#pragma unroll
    for (int m = 0; m < 4; ++m)
#pragma unroll
      for (int n = 0; n < 4; ++n)
        acc[m][n] = __builtin_amdgcn_mfma_f32_16x16x32_bf16(af[m], bfr[n], acc[m][n], 0, 0, 0);
    __syncthreads();
  }

  float bias_n[4];
#pragma unroll
  for (int n = 0; n < 4; ++n) bias_n[n] = bias[col0 + wc * 64 + n * 16 + c15];

#pragma unroll
  for (int m = 0; m < 4; ++m) {
#pragma unroll
    for (int jr = 0; jr < 4; ++jr) {
      int r_g = row0 + wr * 64 + m * 16 + q4 * 4 + jr;
      float v[4];
#pragma unroll
      for (int n = 0; n < 4; ++n) {
        int c_g = col0 + wc * 64 + n * 16 + c15;
        float val = acc[m][n][jr] + bias_n[n];
        C[(size_t)r_g * ldc + c_g] = val;
        v[n] = val;
      }
      if (SM_EPI) {
        float mx = fmaxf(fmaxf(v[0], v[1]), fmaxf(v[2], v[3]));
        float s = __expf(v[0] - mx) + __expf(v[1] - mx) + __expf(v[2] - mx) + __expf(v[3] - mx);
#pragma unroll
        for (int d = 1; d < 16; d <<= 1) {
          float mo = __shfl_xor(mx, d, 64);
          float so = __shfl_xor(s, d, 64);
          float M2 = fmaxf(mx, mo);
          s = s * __expf(mx - M2) + so * __expf(mo - M2);
          mx = M2;
        }
        if (c15 == 0) red[wr * 64 + m * 16 + q4 * 4 + jr][wc] = make_float2(mx, s);
      }
    }
  }
  if (SM_EPI) {
    __syncthreads();
    if (tid < 128) {
      float2 a = red[tid][0], b2 = red[tid][1];
      float M2 = fmaxf(a.x, b2.x);
      float S = a.y * __expf(a.x - M2) + b2.y * __expf(b2.x - M2);
      pmax[(size_t)(row0 + tid) * nch + blockIdx.x] = M2;
      psum[(size_t)(row0 + tid) * nch + blockIdx.x] = S;
    }
  }
}

// ---------------- persistent 2-layer pipelined LSTM ----------------
// R[t] (write-once): [h0(t-1) | h1(t-2)], 32 rows x 2048 cols bf16.
// Tick t: L0 blocks (0..63) compute h0(t) -> R[t+1][:, :1024];
//         L1 blocks (64..127) compute h1(t-1) -> R[t+1][:, 1024:] (+ H1bf).
// Producers store agent-scope (visible at L3); consumers use PLAIN cached
// loads: each R address is written exactly once and first read after the
// write, so the L2 miss fetches fresh data from L3 (write-once coherence).

#define RED(w_, rt_, q_, r_, c_) red[(((((w_)*2 + (rt_)) * 4 + (q_)) * 16 + (r_)) * 16 + (c_))]

template <int KH>
DEV void lstm_tick(const u16* __restrict__ hread,   // [32][2048] bf16
                   const u16* __restrict__ WT, int koffw,
                   const float* __restrict__ zb, int zb_stride,
                   float* __restrict__ c_lds, float* __restrict__ red,
                   u16* __restrict__ hwr,            // R[t+1] col-slice base (stride 2048)
                   u16* __restrict__ h1out, int wgu) {
  int tid = threadIdx.x, lane = tid & 63, w = tid >> 6;
  int c15 = lane & 15, q4 = lane >> 4;
  constexpr int NIT = KH / 128;    // k-steps per wave
  int k0 = w * (KH / 4);

  // prefetch z-bias for this thread's epilogue pairs (hides L3 latency)
  int eb = tid >> 3, ej = (tid & 7) * 2;
  float zpre[8];
#pragma unroll
  for (int q = 0; q < 4; ++q) {
    int g = q * 1024 + wgu * 16 + ej;
    const float* src = zb_stride ? (zb + (size_t)eb * zb_stride + g) : (zb + g);
    float2 v = *(const float2*)src;
    zpre[q * 2] = v.x; zpre[q * 2 + 1] = v.y;
  }

  // issue ALL h loads up front (plain cached loads; write-once buffers)
  short8 afr[NIT][2];
#pragma unroll
  for (int it = 0; it < NIT; ++it) {
    int k = k0 + it * 32 + q4 * 8;
#pragma unroll
    for (int rt = 0; rt < 2; ++rt)
      afr[it][rt] = *(const short8*)(hread + (size_t)(rt * 16 + c15) * 2048 + k);
  }

  const u16* bp[4];
#pragma unroll
  for (int q = 0; q < 4; ++q)
    bp[q] = WT + (size_t)(q * 1024 + wgu * 16 + c15) * 2048 + koffw + q4 * 8;

  f32x4 acc[2][4];
#pragma unroll
  for (int rt = 0; rt < 2; ++rt)
#pragma unroll
    for (int q = 0; q < 4; ++q) acc[rt][q] = (f32x4){0.f, 0.f, 0.f, 0.f};

#pragma unroll
  for (int it = 0; it < NIT; ++it) {
    int kbase = k0 + it * 32;
#pragma unroll
    for (int q = 0; q < 4; ++q) {
      short8 b8 = *(const short8*)(bp[q] + kbase);   // weights: L2-resident
#pragma unroll
      for (int rt = 0; rt < 2; ++rt)
        acc[rt][q] = __builtin_amdgcn_mfma_f32_16x16x32_bf16(afr[it][rt], b8, acc[rt][q], 0, 0, 0);
    }
  }

  // cross-wave K reduction via LDS
#pragma unroll
  for (int rt = 0; rt < 2; ++rt)
#pragma unroll
    for (int q = 0; q < 4; ++q)
#pragma unroll
      for (int jr = 0; jr < 4; ++jr)
        RED(w, rt, q, q4 * 4 + jr, c15) = acc[rt][q][jr];
  __syncthreads();

  // epilogue: 256 threads x 2 adjacent units
  int rt = eb >> 4, rr = eb & 15;
  float hv[2];
#pragma unroll
  for (int e = 0; e < 2; ++e) {
    int uu = ej + e;
    float z[4];
#pragma unroll
    for (int q = 0; q < 4; ++q) {
      float s = RED(0, rt, q, rr, uu) + RED(1, rt, q, rr, uu) +
                RED(2, rt, q, rr, uu) + RED(3, rt, q, rr, uu);
      z[q] = s + zpre[q * 2 + e];
    }
    float c_old = c_lds[eb * 16 + uu];
    float gi = sigm(z[0]);
    float gj = tanhf(z[1]);
    float gf = sigm(z[2] + 1.f);   // forget_bias = 1.0
    float go = sigm(z[3]);
    float c2 = c_old * gf + gi * gj;
    hv[e] = go * tanhf(c2);
    c_lds[eb * 16 + uu] = c2;      // c-state persists in LDS across ticks
  }
  unsigned int pack = (unsigned int)f2bf(hv[0]) | ((unsigned int)f2bf(hv[1]) << 16);
  __hip_atomic_store((unsigned int*)(hwr + (size_t)eb * 2048 + ej), pack,
                     __ATOMIC_RELAXED, __HIP_MEMORY_SCOPE_AGENT);
  if (h1out)
    *(unsigned int*)(h1out + (size_t)eb * (T * H) + ej) = pack;  // H1 (normal store)
}

__global__ __launch_bounds__(256, 1)
void k_lstm_persistent(const u16* __restrict__ W0T, const u16* __restrict__ W1T,
                       const float* __restrict__ xp0, const float* __restrict__ b1,
                       u16* __restrict__ hseq, u16* __restrict__ H1bf,
                       int* __restrict__ sync) {
  __shared__ float red[4 * 2 * 4 * 16 * 16];   // 32KB
  __shared__ float c_lds[512];

  int tid = threadIdx.x;
  int wg = blockIdx.x;
  bool isL0 = wg < 64;
  int wgu = isL0 ? wg : wg - 64;

  c_lds[tid] = 0.f;
  c_lds[tid + 256] = 0.f;
  __syncthreads();

  for (int tick = 0; tick <= T; ++tick) {
    const u16* hread = hseq + (size_t)tick * RSTRIDE;
    u16* hwr = hseq + (size_t)(tick + 1) * RSTRIDE;

    if (isL0) {
      if (tick < T)
        lstm_tick<1024>(hread, W0T, 1024,
                        xp0 + (size_t)tick * 32 * G, G,
                        c_lds, red, hwr + wgu * 16, nullptr, wgu);
    } else {
      if (tick >= 1)
        lstm_tick<2048>(hread, W1T, 0,
                        b1, 0,
                        c_lds, red, hwr + 1024 + wgu * 16,
                        H1bf + (size_t)(tick - 1) * H + wgu * 16, wgu);
    }

    // hierarchical grid barrier: 8 group counters -> master -> release word.
    // __syncthreads drains vmcnt (agent h-stores acked at coherence point).
    __syncthreads();
    if (tid == 0) {
      int g = wg >> 4;
      int old = __hip_atomic_fetch_add(sync + g * 64, 1,
                                       __ATOMIC_RELAXED, __HIP_MEMORY_SCOPE_AGENT);
      if (old == 16 * (tick + 1) - 1) {
        int m = __hip_atomic_fetch_add(sync + 8 * 64, 1,
                                       __ATOMIC_RELAXED, __HIP_MEMORY_SCOPE_AGENT);
        if (m == 8 * (tick + 1) - 1)
          __hip_atomic_store(sync + 9 * 64, tick + 1,
                             __ATOMIC_RELAXED, __HIP_MEMORY_SCOPE_AGENT);
      }
      while (__hip_atomic_load(sync + 9 * 64,
                               __ATOMIC_RELAXED, __HIP_MEMORY_SCOPE_AGENT) < tick + 1)
        __builtin_amdgcn_s_sleep(4);
    }
    __builtin_amdgcn_sched_barrier(0);
    __syncthreads();
  }
}

// ---------------- softmax finalize ----------------
__global__ void k_rowfin(const float* __restrict__ pmax, const float* __restrict__ psum,
                         const float* __restrict__ Cl, const int* __restrict__ targets,
                         float* __restrict__ loss) {
  int row = blockIdx.x;
  int tid = threadIdx.x, lane = tid & 63, w = tid >> 6;
  float mx = -1e30f, s = 0.f;
  if (tid < NCH) { mx = pmax[(size_t)row * NCH + tid]; s = psum[(size_t)row * NCH + tid]; }
#pragma unroll
  for (int d = 1; d < 64; d <<= 1) {
    float mo = __shfl_xor(mx, d, 64);
    float so = __shfl_xor(s, d, 64);
    float M2 = fmaxf(mx, mo);
    s = s * __expf(mx - M2) + so * __expf(mo - M2);
    mx = M2;
  }
  __shared__ float2 wred[4];
  if (lane == 0) wred[w] = make_float2(mx, s);
  __syncthreads();
  if (tid == 0) {
    float M = wred[0].x, S = wred[0].y;
#pragma unroll
    for (int i = 1; i < 4; ++i) {
      float M2 = fmaxf(M, wred[i].x);
      S = S * __expf(M - M2) + wred[i].y * __expf(wred[i].x - M2);
      M = M2;
    }
    float logZ = M + logf(S);
    int tgt = targets[row];
    float xt = Cl[(size_t)row * V + tgt];
    loss[row] = logZ - xt;
  }
}

__global__ void k_cost(const float* __restrict__ loss, float* __restrict__ out) {
  int tid = threadIdx.x, lane = tid & 63, w = tid >> 6;
  float s = 0.f;
  for (int i = tid; i < BT; i += 256) s += loss[i];
#pragma unroll
  for (int d = 1; d < 64; d <<= 1) s += __shfl_xor(s, d, 64);
  __shared__ float ws4[4];
  if (lane == 0) ws4[w] = s;
  __syncthreads();
  if (tid == 0) out[0] = (ws4[0] + ws4[1] + ws4[2] + ws4[3]) * (1.0f / B);
}

// ---------------- host ----------------
extern "C" void kernel_launch(void* const* d_in, const int* in_sizes, int n_in,
                              void* d_out, int out_size, void* d_ws, size_t ws_size,
                              hipStream_t stream) {
  const int*   input_data = (const int*)d_in[0];
  const int*   targets    = (const int*)d_in[1];
  const float* emb        = (const float*)d_in[2];
  const float* softmax_b  = (const float*)d_in[3];
  const float* W0         = (const float*)d_in[4];
  const float* b0         = (const float*)d_in[5];
  const float* W1         = (const float*)d_in[6];
  const float* b1         = (const float*)d_in[7];
  float* out = (float*)d_out;
  char*  ws  = (char*)d_ws;

  u16*   W0T  = (u16*)(ws + OFF_W0T);
  u16*   W1T  = (u16*)(ws + OFF_W1T);
  u16*   Ebf  = (u16*)(ws + OFF_EBF);
  u16*   Xbf  = (u16*)(ws + OFF_XBF);
  float* xp0  = (float*)(ws + OFF_XP0);
  u16*   H1bf = (u16*)(ws + OFF_H1);
  u16*   hseq = (u16*)(ws + OFF_HSEQ);
  int*   sync = (int*)(ws + OFF_SYNC);
  float* pmax = (float*)(ws + OFF_PMAX);
  float* psum = (float*)(ws + OFF_PSUM);
  float* lossb= (float*)(ws + OFF_LOSS);

  // prep: weight transposes (bf16), embedding convert, X gather, R[0..1]/sync zero
  k_transpose_cvt<<<dim3(G / 32, 2048 / 32), 256, 0, stream>>>(W0, W0T, 2048, G);
  k_transpose_cvt<<<dim3(G / 32, 2048 / 32), 256, 0, stream>>>(W1, W1T, 2048, G);
  k_cvt_bf16<<<2048, 256, 0, stream>>>(emb, Ebf, V * H / 4);
  k_gather_x<<<BT, 256, 0, stream>>>(emb, input_data, Xbf);
  k_zero<<<64, 256, 0, stream>>>((unsigned int*)(ws + OFF_HSEQ), RSTRIDE);  // R[0],R[1]
  k_zero<<<1, 256, 0, stream>>>((unsigned int*)(ws + OFF_SYNC), 1024);

  // xpart0 = X @ W0[0:1024,:] + b0   (f32 out, row = t*32+b)
  k_gemm<false><<<dim3(G / 128, BT / 128), 256, 0, stream>>>(
      Xbf, H, W0T, 2048, xp0, G, b0, H, nullptr, nullptr, 0);

  // persistent pipelined LSTM: 257 ticks, hierarchical barrier each
  k_lstm_persistent<<<dim3(NWG), dim3(256), 0, stream>>>(
      W0T, W1T, xp0, b1, hseq, H1bf, sync);

  // logits = H1 @ E^T + softmax_b, fused online-softmax partials
  k_gemm<true><<<dim3(V / 128, BT / 128), 256, 0, stream>>>(
      H1bf, H, Ebf, H, out, V, softmax_b, H, pmax, psum, NCH);

  // per-row logZ + NLL, then cost = sum/B appended after logits
  k_rowfin<<<BT, 256, 0, stream>>>(pmax, psum, out, targets, lossb);
  k_cost<<<1, 256, 0, stream>>>(lossb, out + (size_t)BT * V);
}

// Round 4
// 3001.027 us; speedup vs baseline: 3.2618x; 1.6663x over previous
//
#include <hip/hip_runtime.h>
#include <hip/hip_bf16.h>

#define DEV static __device__ __forceinline__

typedef unsigned short u16;
typedef unsigned long long u64;
typedef __attribute__((ext_vector_type(8))) short short8;   // 8 bf16 (4 VGPRs) MFMA frag
typedef __attribute__((ext_vector_type(4))) float f32x4;    // MFMA accumulator

constexpr int V = 32000, H = 1024, B = 32, T = 256;
constexpr int BT = B * T;       // 8192 rows
constexpr int G  = 4 * H;       // 4096 gates
constexpr int NCH = V / 128;    // 250 col-chunks for softmax partials
constexpr int NWG2 = 256;       // persistent LSTM blocks (128 L0 + 128 L1), 1/CU
constexpr int RSTRIDE = 32 * 2048 + 2048;  // u16 per h-buffer (132KB incl 4KB pad)

// ---------------- workspace layout (bytes) ----------------
constexpr size_t SZ_WT    = (size_t)G * 2048 * 2;            // [4096][2048] bf16
constexpr size_t OFF_W0T  = 0;
constexpr size_t OFF_W1T  = OFF_W0T + SZ_WT;
constexpr size_t OFF_EBF  = OFF_W1T + SZ_WT;                 // [32000][1024] bf16
constexpr size_t OFF_XBF  = OFF_EBF + (size_t)V * H * 2;     // [8192][1024] bf16 (row = t*32+b)
constexpr size_t OFF_XP0  = OFF_XBF + (size_t)BT * H * 2;    // bf16 perm [t][wgu][b][q*8+uu]
constexpr size_t OFF_H1   = OFF_XP0 + (size_t)BT * G * 2;    // [8192][1024] bf16 (row = b*256+t)
constexpr size_t OFF_HSEQ = OFF_H1 + (size_t)BT * H * 2;     // R[0..T+1], write-once per tick
constexpr size_t SZ_HSEQ  = (size_t)(T + 2) * RSTRIDE * 2;
constexpr size_t OFF_SYNC = OFF_HSEQ + SZ_HSEQ;              // barrier counters (8KB)
constexpr size_t OFF_PMAX = OFF_SYNC + 8192;                 // [8192][250] f32
constexpr size_t OFF_PSUM = OFF_PMAX + (size_t)BT * NCH * 4;
constexpr size_t OFF_LOSS = OFF_PSUM + (size_t)BT * NCH * 4; // [8192] f32

DEV u16 f2bf(float x) {  // RNE f32 -> bf16 bits
  union { float f; unsigned int u; } v; v.f = x;
  unsigned int r = v.u + 0x7fffu + ((v.u >> 16) & 1u);
  return (u16)(r >> 16);
}
DEV float bf2f(u16 b) {
  union { unsigned int u; float f; } v; v.u = ((unsigned int)b) << 16;
  return v.f;
}
DEV float sigm(float x) { return 1.f / (1.f + expf(-x)); }

DEV void gload_lds16(const u16* g, u16* l) {
  __builtin_amdgcn_global_load_lds(
      (__attribute__((address_space(1))) void*)g,
      (__attribute__((address_space(3))) void*)l, 16, 0, 0);
}

// ---------------- prep kernels ----------------

__global__ void k_transpose_cvt(const float* __restrict__ in, u16* __restrict__ out,
                                int R, int C) {
  __shared__ float tile[32][33];
  int bc = blockIdx.x * 32, br = blockIdx.y * 32;
  int tx = threadIdx.x & 31, ty0 = threadIdx.x >> 5;
#pragma unroll
  for (int i = 0; i < 4; ++i) {
    int ty = ty0 + i * 8;
    tile[ty][tx] = in[(size_t)(br + ty) * C + bc + tx];
  }
  __syncthreads();
#pragma unroll
  for (int i = 0; i < 4; ++i) {
    int ty = ty0 + i * 8;
    out[(size_t)(bc + ty) * R + br + tx] = f2bf(tile[tx][ty]);
  }
}

__global__ void k_cvt_bf16(const float* __restrict__ in, u16* __restrict__ out, int n4) {
  int i = blockIdx.x * blockDim.x + threadIdx.x;
  int stride = gridDim.x * blockDim.x;
  for (; i < n4; i += stride) {
    float4 v = ((const float4*)in)[i];
    ushort4 o;
    o.x = f2bf(v.x); o.y = f2bf(v.y); o.z = f2bf(v.z); o.w = f2bf(v.w);
    ((ushort4*)out)[i] = o;
  }
}

__global__ void k_gather_x(const float* __restrict__ emb, const int* __restrict__ inp,
                           u16* __restrict__ Xbf) {
  int row = blockIdx.x;
  int t = row >> 5, b = row & 31;
  int tok = inp[b * T + t];
  const float4* src = (const float4*)(emb + (size_t)tok * H);
  ushort4* dst = (ushort4*)(Xbf + (size_t)row * H);
  float4 v = src[threadIdx.x];
  ushort4 o;
  o.x = f2bf(v.x); o.y = f2bf(v.y); o.z = f2bf(v.z); o.w = f2bf(v.w);
  dst[threadIdx.x] = o;
}

__global__ void k_zero(unsigned int* __restrict__ p, int nwords) {
  int i = blockIdx.x * blockDim.x + threadIdx.x;
  int stride = gridDim.x * blockDim.x;
  for (; i < nwords; i += stride) p[i] = 0u;
}

// ---------------- 128x128 bf16 MFMA GEMM (m97 structure) ----------------
// CMODE 0: C f32 [M][ldc].  CMODE 1: C bf16, permuted [t][wgu][b][q*8+uu]
// (block-contiguous xp0 layout for the persistent LSTM's bias reads).
template <bool SM_EPI, int CMODE>
__global__ __launch_bounds__(256)
void k_gemm(const u16* __restrict__ A, int lda,
            const u16* __restrict__ Bt, int ldb,
            float* __restrict__ C, int ldc,
            const float* __restrict__ bias, int K,
            float* __restrict__ pmax, float* __restrict__ psum, int nch) {
  __shared__ alignas(16) u16 ldsA[128 * 32];
  __shared__ alignas(16) u16 ldsB[128 * 32];
  __shared__ float2 red[128][2];

  int tid = threadIdx.x, lane = tid & 63, w = tid >> 6;
  int row0 = blockIdx.y * 128, col0 = blockIdx.x * 128;
  int wr = w >> 1, wc = w & 1;
  int c15 = lane & 15, q4 = lane >> 4;

  const u16* ag[2]; const u16* bg[2];
#pragma unroll
  for (int j = 0; j < 2; ++j) {
    int r = (j * 4 + w) * 16 + (lane >> 2);
    int k = (lane & 3) * 8;
    ag[j] = A + (size_t)(row0 + r) * lda + k;
    bg[j] = Bt + (size_t)(col0 + r) * ldb + k;
  }
  u16* lA0 = ldsA + (size_t)(0 + w) * 512;
  u16* lA1 = ldsA + (size_t)(4 + w) * 512;
  u16* lB0 = ldsB + (size_t)(0 + w) * 512;
  u16* lB1 = ldsB + (size_t)(4 + w) * 512;

  f32x4 acc[4][4];
#pragma unroll
  for (int m = 0; m < 4; ++m)
#pragma unroll
    for (int n = 0; n < 4; ++n) acc[m][n] = (f32x4){0.f, 0.f, 0.f, 0.f};

  int nk = K >> 5;
  for (int kk = 0; kk < nk; ++kk) {
    int kb = kk * 32;
    gload_lds16(ag[0] + kb, lA0);
    gload_lds16(ag[1] + kb, lA1);
    gload_lds16(bg[0] + kb, lB0);
    gload_lds16(bg[1] + kb, lB1);
    __syncthreads();

    short8 af[4], bfr[4];
#pragma unroll
    for (int m = 0; m < 4; ++m)
      af[m] = *(const short8*)(ldsA + (wr * 64 + m * 16 + c15) * 32 + q4 * 8);
#pragma unroll
    for (int n = 0; n < 4; ++n)
      bfr[n] = *(const short8*)(ldsB + (wc * 64 + n * 16 + c15) * 32 + q4 * 8);
#pragma unroll
    for (int m = 0; m < 4; ++m)
#pragma unroll
      for (int n = 0; n < 4; ++n)
        acc[m][n] = __builtin_amdgcn_mfma_f32_16x16x32_bf16(af[m], bfr[n], acc[m][n], 0, 0, 0);
    __syncthreads();
  }

  float bias_n[4];
#pragma unroll
  for (int n = 0; n < 4; ++n) bias_n[n] = bias[col0 + wc * 64 + n * 16 + c15];

#pragma unroll
  for (int m = 0; m < 4; ++m) {
#pragma unroll
    for (int jr = 0; jr < 4; ++jr) {
      int r_g = row0 + wr * 64 + m * 16 + q4 * 4 + jr;
      float v[4];
#pragma unroll
      for (int n = 0; n < 4; ++n) {
        int c_g = col0 + wc * 64 + n * 16 + c15;
        float val = acc[m][n][jr] + bias_n[n];
        if (CMODE == 0) {
          C[(size_t)r_g * ldc + c_g] = val;
        } else {
          int tt = r_g >> 5, bb = r_g & 31;
          int q = c_g >> 10, wgup = (c_g & 1023) >> 3, uu = c_g & 7;
          ((u16*)C)[((((size_t)tt * 128 + wgup) * 32 + bb) * 32) + q * 8 + uu] = f2bf(val);
        }
        v[n] = val;
      }
      if (SM_EPI) {
        float mx = fmaxf(fmaxf(v[0], v[1]), fmaxf(v[2], v[3]));
        float s = __expf(v[0] - mx) + __expf(v[1] - mx) + __expf(v[2] - mx) + __expf(v[3] - mx);
#pragma unroll
        for (int d = 1; d < 16; d <<= 1) {
          float mo = __shfl_xor(mx, d, 64);
          float so = __shfl_xor(s, d, 64);
          float M2 = fmaxf(mx, mo);
          s = s * __expf(mx - M2) + so * __expf(mo - M2);
          mx = M2;
        }
        if (c15 == 0) red[wr * 64 + m * 16 + q4 * 4 + jr][wc] = make_float2(mx, s);
      }
    }
  }
  if (SM_EPI) {
    __syncthreads();
    if (tid < 128) {
      float2 a = red[tid][0], b2 = red[tid][1];
      float M2 = fmaxf(a.x, b2.x);
      float S = a.y * __expf(a.x - M2) + b2.y * __expf(b2.x - M2);
      pmax[(size_t)(row0 + tid) * nch + blockIdx.x] = M2;
      psum[(size_t)(row0 + tid) * nch + blockIdx.x] = S;
    }
  }
}

// ---------------- persistent LSTM: weights in registers ----------------
// 256 blocks: 0..127 = layer0 (8 units each), 128..255 = layer1 (8 units).
// Each block's 4 waves own K-slices; weight slice (32KB/wave) lives in VGPRs
// (short8 wfr[2][NKC], statically indexed, loaded once). Per tick: read h
// (L2-shared), MFMA, LDS cross-wave K-reduce, gate math (c in register),
// agent-scope h store, hierarchical grid barrier.

#define RED(w_, bt_, nt_, r_, c_) red[((((w_)*2 + (bt_)) * 2 + (nt_)) * 16 + (r_)) * 16 + (c_)]

DEV void grid_barrier(int* __restrict__ sync, int wg, int gen) {
  __syncthreads();   // drains vmcnt: agent h-stores acked at coherence point
  if (threadIdx.x == 0) {
    int g = wg >> 4;  // 16 groups of 16
    int old = __hip_atomic_fetch_add(sync + g * 64, 1,
                                     __ATOMIC_RELAXED, __HIP_MEMORY_SCOPE_AGENT);
    if (old == 16 * gen - 1) {
      int m = __hip_atomic_fetch_add(sync + 16 * 64, 1,
                                     __ATOMIC_RELAXED, __HIP_MEMORY_SCOPE_AGENT);
      if (m == 16 * gen - 1)
        __hip_atomic_store(sync + 17 * 64, gen,
                           __ATOMIC_RELAXED, __HIP_MEMORY_SCOPE_AGENT);
    }
    while (__hip_atomic_load(sync + 17 * 64,
                             __ATOMIC_RELAXED, __HIP_MEMORY_SCOPE_AGENT) < gen)
      __builtin_amdgcn_s_sleep(2);
  }
  __builtin_amdgcn_sched_barrier(0);
  __syncthreads();
}

template <int KH, bool IS_L0>
DEV void lstm_role(const u16* __restrict__ WT,      // [4096][2048] bf16
                   const u16* __restrict__ xp0p,    // bf16 perm (L0) or null
                   const float* __restrict__ zb1,   // b1 (L1) or null
                   u16* __restrict__ hseq, u16* __restrict__ H1bf,
                   int* __restrict__ sync, float* __restrict__ red,
                   int wgu, int wg) {
  constexpr int KOFF = IS_L0 ? 1024 : 0;   // weight-k offset (h-part of W0)
  constexpr int KS = KH / 4;               // per-wave K slice
  constexpr int NKC = KS / 32;             // k-chunks per wave (8 or 16)
  int tid = threadIdx.x, lane = tid & 63, w = tid >> 6;
  int c15 = lane & 15, q4 = lane >> 4;
  int eb = tid >> 3, eu = tid & 7;         // epilogue identity: (b, unit)

  // ---- preload weight slice into registers (once) ----
  short8 wfr[2][NKC];
#pragma unroll
  for (int nt = 0; nt < 2; ++nt) {
    int lr = nt * 16 + c15;                // local row = gate*8 + unit
    const u16* rp = WT + (size_t)((lr >> 3) * 1024 + wgu * 8 + (lr & 7)) * 2048
                    + KOFF + w * KS + q4 * 8;
#pragma unroll
    for (int kc = 0; kc < NKC; ++kc)
      wfr[nt][kc] = *(const short8*)(rp + kc * 32);
  }

  float zpc[4];
  if (!IS_L0) {
#pragma unroll
    for (int q = 0; q < 4; ++q) zpc[q] = zb1[q * 1024 + wgu * 8 + eu];
  }
  float creg = 0.f;                        // c-state lives in a register

  for (int tick = 0; tick <= T; ++tick) {
    if (IS_L0 ? (tick < T) : (tick >= 1)) {
      float zp[4];
      if (IS_L0) {
#pragma unroll
        for (int q = 0; q < 4; ++q)
          zp[q] = bf2f(xp0p[((((size_t)tick * 128 + wgu) * 32 + eb) * 32) + q * 8 + eu]);
      } else {
#pragma unroll
        for (int q = 0; q < 4; ++q) zp[q] = zpc[q];
      }

      const u16* hread = hseq + (size_t)tick * RSTRIDE;
      f32x4 acc[2][2];
#pragma unroll
      for (int bt = 0; bt < 2; ++bt)
#pragma unroll
        for (int nt = 0; nt < 2; ++nt) acc[bt][nt] = (f32x4){0.f, 0.f, 0.f, 0.f};

#pragma unroll
      for (int kc = 0; kc < NKC; ++kc) {
        int kh = w * KS + kc * 32 + q4 * 8;
        short8 a0 = *(const short8*)(hread + (size_t)c15 * 2048 + kh);
        short8 a1 = *(const short8*)(hread + (size_t)(16 + c15) * 2048 + kh);
        acc[0][0] = __builtin_amdgcn_mfma_f32_16x16x32_bf16(a0, wfr[0][kc], acc[0][0], 0, 0, 0);
        acc[0][1] = __builtin_amdgcn_mfma_f32_16x16x32_bf16(a0, wfr[1][kc], acc[0][1], 0, 0, 0);
        acc[1][0] = __builtin_amdgcn_mfma_f32_16x16x32_bf16(a1, wfr[0][kc], acc[1][0], 0, 0, 0);
        acc[1][1] = __builtin_amdgcn_mfma_f32_16x16x32_bf16(a1, wfr[1][kc], acc[1][1], 0, 0, 0);
      }

      // cross-wave K reduction via LDS
#pragma unroll
      for (int bt = 0; bt < 2; ++bt)
#pragma unroll
        for (int nt = 0; nt < 2; ++nt)
#pragma unroll
          for (int jr = 0; jr < 4; ++jr)
            RED(w, bt, nt, q4 * 4 + jr, c15) = acc[bt][nt][jr];
      __syncthreads();

      // epilogue: thread = (b=eb, unit=eu)
      int bt = eb >> 4, rr = eb & 15;
      float z[4];
#pragma unroll
      for (int q = 0; q < 4; ++q) {
        int lr = q * 8 + eu, nt = lr >> 4, cc = lr & 15;
        z[q] = RED(0, bt, nt, rr, cc) + RED(1, bt, nt, rr, cc) +
               RED(2, bt, nt, rr, cc) + RED(3, bt, nt, rr, cc) + zp[q];
      }
      float gi = sigm(z[0]);
      float gj = tanhf(z[1]);
      float gf = sigm(z[2] + 1.f);   // forget_bias = 1.0
      float go = sigm(z[3]);
      creg = creg * gf + gi * gj;
      float hv = go * tanhf(creg);

      int hb = (int)f2bf(hv);
      int hp = __shfl_xor(hb, 1, 64);  // partner unit (eu^1), same b
      if (!(tid & 1)) {
        unsigned int pack = (unsigned int)(u16)hb | ((unsigned int)(u16)hp << 16);
        u16* hwr = hseq + (size_t)(tick + 1) * RSTRIDE + (IS_L0 ? 0 : 1024);
        __hip_atomic_store((unsigned int*)(hwr + (size_t)eb * 2048 + wgu * 8 + eu), pack,
                           __ATOMIC_RELAXED, __HIP_MEMORY_SCOPE_AGENT);
        if (!IS_L0)
          *(unsigned int*)(H1bf + ((size_t)eb * T + (tick - 1)) * H + wgu * 8 + eu) = pack;
      }
    }
    grid_barrier(sync, wg, tick + 1);
  }
}

__global__ __launch_bounds__(256, 1)
void k_lstm_persistent(const u16* __restrict__ W0T, const u16* __restrict__ W1T,
                       const u16* __restrict__ xp0p, const float* __restrict__ b1,
                       u16* __restrict__ hseq, u16* __restrict__ H1bf,
                       int* __restrict__ sync) {
  __shared__ float red[4 * 2 * 2 * 16 * 16];   // 16KB
  int wg = blockIdx.x;
  if (wg < 128)
    lstm_role<1024, true>(W0T, xp0p, nullptr, hseq, H1bf, sync, red, wg, wg);
  else
    lstm_role<2048, false>(W1T, nullptr, b1, hseq, H1bf, sync, red, wg - 128, wg);
}

// ---------------- softmax finalize ----------------
__global__ void k_rowfin(const float* __restrict__ pmax, const float* __restrict__ psum,
                         const float* __restrict__ Cl, const int* __restrict__ targets,
                         float* __restrict__ loss) {
  int row = blockIdx.x;
  int tid = threadIdx.x, lane = tid & 63, w = tid >> 6;
  float mx = -1e30f, s = 0.f;
  if (tid < NCH) { mx = pmax[(size_t)row * NCH + tid]; s = psum[(size_t)row * NCH + tid]; }
#pragma unroll
  for (int d = 1; d < 64; d <<= 1) {
    float mo = __shfl_xor(mx, d, 64);
    float so = __shfl_xor(s, d, 64);
    float M2 = fmaxf(mx, mo);
    s = s * __expf(mx - M2) + so * __expf(mo - M2);
    mx = M2;
  }
  __shared__ float2 wred[4];
  if (lane == 0) wred[w] = make_float2(mx, s);
  __syncthreads();
  if (tid == 0) {
    float M = wred[0].x, S = wred[0].y;
#pragma unroll
    for (int i = 1; i < 4; ++i) {
      float M2 = fmaxf(M, wred[i].x);
      S = S * __expf(M - M2) + wred[i].y * __expf(wred[i].x - M2);
      M = M2;
    }
    float logZ = M + logf(S);
    int tgt = targets[row];
    float xt = Cl[(size_t)row * V + tgt];
    loss[row] = logZ - xt;
  }
}

__global__ void k_cost(const float* __restrict__ loss, float* __restrict__ out) {
  int tid = threadIdx.x, lane = tid & 63, w = tid >> 6;
  float s = 0.f;
  for (int i = tid; i < BT; i += 256) s += loss[i];
#pragma unroll
  for (int d = 1; d < 64; d <<= 1) s += __shfl_xor(s, d, 64);
  __shared__ float ws4[4];
  if (lane == 0) ws4[w] = s;
  __syncthreads();
  if (tid == 0) out[0] = (ws4[0] + ws4[1] + ws4[2] + ws4[3]) * (1.0f / B);
}

// ---------------- host ----------------
extern "C" void kernel_launch(void* const* d_in, const int* in_sizes, int n_in,
                              void* d_out, int out_size, void* d_ws, size_t ws_size,
                              hipStream_t stream) {
  const int*   input_data = (const int*)d_in[0];
  const int*   targets    = (const int*)d_in[1];
  const float* emb        = (const float*)d_in[2];
  const float* softmax_b  = (const float*)d_in[3];
  const float* W0         = (const float*)d_in[4];
  const float* b0         = (const float*)d_in[5];
  const float* W1         = (const float*)d_in[6];
  const float* b1         = (const float*)d_in[7];
  float* out = (float*)d_out;
  char*  ws  = (char*)d_ws;

  u16*   W0T  = (u16*)(ws + OFF_W0T);
  u16*   W1T  = (u16*)(ws + OFF_W1T);
  u16*   Ebf  = (u16*)(ws + OFF_EBF);
  u16*   Xbf  = (u16*)(ws + OFF_XBF);
  u16*   xp0p = (u16*)(ws + OFF_XP0);
  u16*   H1bf = (u16*)(ws + OFF_H1);
  u16*   hseq = (u16*)(ws + OFF_HSEQ);
  int*   sync = (int*)(ws + OFF_SYNC);
  float* pmax = (float*)(ws + OFF_PMAX);
  float* psum = (float*)(ws + OFF_PSUM);
  float* lossb= (float*)(ws + OFF_LOSS);

  // prep: weight transposes (bf16), embedding convert, X gather, R[0..1]/sync zero
  k_transpose_cvt<<<dim3(G / 32, 2048 / 32), 256, 0, stream>>>(W0, W0T, 2048, G);
  k_transpose_cvt<<<dim3(G / 32, 2048 / 32), 256, 0, stream>>>(W1, W1T, 2048, G);
  k_cvt_bf16<<<2048, 256, 0, stream>>>(emb, Ebf, V * H / 4);
  k_gather_x<<<BT, 256, 0, stream>>>(emb, input_data, Xbf);
  k_zero<<<64, 256, 0, stream>>>((unsigned int*)(ws + OFF_HSEQ), RSTRIDE);  // R[0],R[1]
  k_zero<<<1, 256, 0, stream>>>((unsigned int*)(ws + OFF_SYNC), 2048);

  // xp0p = X @ W0[0:1024,:] + b0  (bf16, block-permuted layout)
  k_gemm<false, 1><<<dim3(G / 128, BT / 128), 256, 0, stream>>>(
      Xbf, H, W0T, 2048, (float*)xp0p, G, b0, H, nullptr, nullptr, 0);

  // persistent pipelined LSTM: 257 ticks, weights in VGPRs
  k_lstm_persistent<<<dim3(NWG2), dim3(256), 0, stream>>>(
      W0T, W1T, xp0p, b1, hseq, H1bf, sync);

  // logits = H1 @ E^T + softmax_b, fused online-softmax partials
  k_gemm<true, 0><<<dim3(V / 128, BT / 128), 256, 0, stream>>>(
      H1bf, H, Ebf, H, out, V, softmax_b, H, pmax, psum, NCH);

  // per-row logZ + NLL, then cost = sum/B appended after logits
  k_rowfin<<<BT, 256, 0, stream>>>(pmax, psum, out, targets, lossb);
  k_cost<<<1, 256, 0, stream>>>(lossb, out + (size_t)BT * V);
}